// Round 14
// baseline (572.008 us; speedup 1.0000x reference)
//
#include <hip/hip_runtime.h>
#include <cfloat>
#include <cmath>

// NoisyTopKRouter eval-mode: logits = x @ W^T, top-2 + softmax over top-2.
// N=131072, D=2048, E=16. Outputs (concatenated flat in d_out as float32):
//   [0 .. 2N)   topk indices (as float values; ref dtype int64)
//   [2N .. 4N)  gating weights (softmax over the two top logits)
//
// BIT-EXACTNESS (round 7): each (row, expert) dot computed by ONE lane over
// all of D, 4 mod-4 fma chains ascending, reduced (c0+c1)+(c2+c3).
//
// Round-14 insight (R11 ~= R13 at 566 despite different compute): fabric BW
// tracks PER-INSTRUCTION contiguity. 1 KB contiguous/instr -> 6.3 TB/s
// (m13/fills); 512 B segments -> ~3.4 (R8); 128 B -> ~2.1 (R11/R13).
// So: 1-wave blocks, 16 rows, PW=256 -> each global_load_lds stages ONE
// row's 1 KB slice: lane i covers base+16i, fully contiguous.
//
//  - LDS: xs[2][16 rows][260 floats] = 33 KB -> 4 blocks/CU. Pitch 65 f4
//    (odd) -> read quad (r+j)%8, 2 addrs/quad = conflict-free (m136).
//  - Wave-private slabs, NO barriers, counted s_waitcnt vmcnt(16).
//  - thread = (r = lane&15, eq = lane>>4): row r, experts 4eq..4eq+3.
//    Each x float read once per 4 experts; DS ~196k cy/CU < HBM 410k.
//  - W: wt[D][16] (pre-transposed, d_ws); per d one f4 at wt4[d*4+eq]:
//    4 distinct addrs spanning 64 B per wave-instr, 16-way broadcast,
//    L1-hot. Known: W shares vmcnt with staging -> first W use per phase
//    may serialize on stage(p+1) (~one latency per phase, bounded).

constexpr int D = 2048;
constexpr int E = 16;
constexpr int BLOCK = 64;           // 1 wave per block
constexpr int RB = 16;              // rows per block
constexpr int PW = 256;             // floats of D per phase (1 KB per row)
constexpr int NP = D / PW;          // 8 phases
constexpr int PITCHF = 260;         // row pitch in floats (65 f4, odd)
constexpr int SLABF = RB * PITCHF;  // 4160 floats per buffer

__global__ void wt_kernel(const float* __restrict__ W, float* __restrict__ wt) {
  const int d = blockIdx.x * blockDim.x + threadIdx.x;
  if (d >= D) return;
  #pragma unroll
  for (int e = 0; e < E; ++e) wt[d * E + e] = W[e * D + d];
}

__global__ __launch_bounds__(BLOCK, 2) void router_kernel(
    const float* __restrict__ x, const float* __restrict__ wt,
    float* __restrict__ out, int N) {
  __shared__ float xs[2][SLABF];    // 33280 B -> 4 blocks/CU

  const int lane = threadIdx.x;     // 0..63
  const int r    = lane & 15;       // row owned by this thread
  const int eq   = lane >> 4;       // expert quad: experts 4eq..4eq+3
  const int waverow = blockIdx.x * RB;
  const int row  = waverow + r;
  if (waverow >= N) return;

  // staging: instr k stages row (waverow+k), cols [p*256, p*256+256):
  // lane i supplies global bytes base + 16*i -> one contiguous 1 KB burst.
  const float* gsrc = x + (size_t)waverow * D + lane * 4;

  auto stage = [&](int p, int buf) {
    float* ld = &xs[buf][0];
    #pragma unroll
    for (int k = 0; k < RB; ++k)
      __builtin_amdgcn_global_load_lds(
          (const __attribute__((address_space(1))) void*)(gsrc + (size_t)k * D + p * PW),
          (__attribute__((address_space(3))) void*)(ld + k * PITCHF), 16, 0, 0);
  };

  const float4* __restrict__ wt4 = reinterpret_cast<const float4*>(wt);

  float a4[4][4];                   // a4[t][i]: chain t (d mod 4), expert 4eq+i
  #pragma unroll
  for (int t = 0; t < 4; ++t)
    #pragma unroll
    for (int i = 0; i < 4; ++i) a4[t][i] = 0.f;

  stage(0, 0);

  #pragma unroll 1
  for (int p = 0; p < NP; ++p) {
    const int cur = p & 1;
    if (p + 1 < NP) {
      stage(p + 1, cur ^ 1);
      // stage(p) [16 oldest] retired; stage(p+1) [16] may remain in flight.
      // W loads of phase p-1 were all consumed -> already retired.
      asm volatile("s_waitcnt vmcnt(16)" ::: "memory");
    } else {
      asm volatile("s_waitcnt vmcnt(0)" ::: "memory");
    }
    __builtin_amdgcn_sched_barrier(0);

    const float* ls = &xs[cur][r * PITCHF];
    const int wb = p * PW * 4;      // f4 index of d = p*256, eq 0

    #pragma unroll 4
    for (int j = 0; j < PW / 4; ++j) {   // 64 j-steps; d = p*256 + 4j + t
      const float4 xq = *reinterpret_cast<const float4*>(ls + 4 * j);
      const float4 w0 = wt4[wb + (4 * j + 0) * 4 + eq];
      const float4 w1 = wt4[wb + (4 * j + 1) * 4 + eq];
      const float4 w2 = wt4[wb + (4 * j + 2) * 4 + eq];
      const float4 w3 = wt4[wb + (4 * j + 3) * 4 + eq];
      a4[0][0] = fmaf(xq.x, w0.x, a4[0][0]);
      a4[0][1] = fmaf(xq.x, w0.y, a4[0][1]);
      a4[0][2] = fmaf(xq.x, w0.z, a4[0][2]);
      a4[0][3] = fmaf(xq.x, w0.w, a4[0][3]);
      a4[1][0] = fmaf(xq.y, w1.x, a4[1][0]);
      a4[1][1] = fmaf(xq.y, w1.y, a4[1][1]);
      a4[1][2] = fmaf(xq.y, w1.z, a4[1][2]);
      a4[1][3] = fmaf(xq.y, w1.w, a4[1][3]);
      a4[2][0] = fmaf(xq.z, w2.x, a4[2][0]);
      a4[2][1] = fmaf(xq.z, w2.y, a4[2][1]);
      a4[2][2] = fmaf(xq.z, w2.z, a4[2][2]);
      a4[2][3] = fmaf(xq.z, w2.w, a4[2][3]);
      a4[3][0] = fmaf(xq.w, w3.x, a4[3][0]);
      a4[3][1] = fmaf(xq.w, w3.y, a4[3][1]);
      a4[3][2] = fmaf(xq.w, w3.z, a4[3][2]);
      a4[3][3] = fmaf(xq.w, w3.w, a4[3][3]);
    }
  }

  // ---- local top-2 over this thread's 4 experts (ascending index,
  //      strict > => lowest index wins ties; proven rounds 8-13) ----
  float m1 = -FLT_MAX, m2 = -FLT_MAX;
  int   i1 = E, i2 = E;
  #pragma unroll
  for (int i = 0; i < 4; ++i) {
    // horizontal sum in the proven order
    const float v = (a4[0][i] + a4[1][i]) + (a4[2][i] + a4[3][i]);
    const int idx = 4 * eq + i;
    const bool gt1 = v > m1;
    const bool gt2 = v > m2;
    m2 = gt1 ? m1 : (gt2 ? v : m2);
    i2 = gt1 ? i1 : (gt2 ? idx : i2);
    m1 = gt1 ? v : m1;
    i1 = gt1 ? idx : i1;
  }

  // ---- butterfly merge across the 4 eq-groups (lane bits 4,5); selection
  //      is rounding-free; tie-break = lowest index (proven rounds 1-13) ----
  #pragma unroll
  for (int mask = 16; mask < 64; mask <<= 1) {
    const float om1 = __shfl_xor(m1, mask);
    const int   oi1 = __shfl_xor(i1, mask);
    const float om2 = __shfl_xor(m2, mask);
    const int   oi2 = __shfl_xor(i2, mask);
    const bool bwin = (om1 > m1) || (om1 == m1 && oi1 < i1);
    const float b1 = bwin ? om1 : m1; const int bi1 = bwin ? oi1 : i1;
    const float l1 = bwin ? m1 : om1; const int li1 = bwin ? i1 : oi1;
    const float b2 = bwin ? om2 : m2; const int bi2 = bwin ? oi2 : i2;
    const bool lwin = (l1 > b2) || (l1 == b2 && li1 < bi2);
    m1 = b1; i1 = bi1;
    m2 = lwin ? l1 : b2; i2 = lwin ? li1 : bi2;
  }

  if (eq == 0) {                    // lanes 0..15: contiguous 128 B stores
    const float ex  = expf(m2 - m1);      // m2 <= m1 -> ex in (0,1]
    const float inv = 1.0f / (1.0f + ex);
    float2* outi = reinterpret_cast<float2*>(out);
    float2* outw = reinterpret_cast<float2*>(out + (size_t)N * 2);
    outi[row] = make_float2((float)i1, (float)i2);
    outw[row] = make_float2(inv, ex * inv);
  }
}

extern "C" void kernel_launch(void* const* d_in, const int* in_sizes, int n_in,
                              void* d_out, int out_size, void* d_ws, size_t ws_size,
                              hipStream_t stream) {
  const float* x = (const float*)d_in[0];
  const float* W = (const float*)d_in[1];
  float* out = (float*)d_out;
  float* wt  = (float*)d_ws;               // W^T staging: D*E*4 = 128 KB
  const int N = in_sizes[0] / D;           // 131072

  wt_kernel<<<D / 256, 256, 0, stream>>>(W, wt);
  router_kernel<<<N / RB, BLOCK, 0, stream>>>(x, wt, out, N);
}